// Round 6
// baseline (323.147 us; speedup 1.0000x reference)
//
#include <hip/hip_runtime.h>

// MHA forward: H=16, N=2048, d_model=1024, d_k=64.
// d_out = [ out (2048x1024 f32) | p_attn (16x2048x2048 f32) ]
// Pipeline: cvt(f32->bf16 + mask bias) -> QKV proj (gload_lds GEMM, V stored
// transposed) -> fused attn (barrier-free: K/V/Q MFMA frags loaded DIRECTLY
// from L2-resident global, wave-private P tile in LDS, XCD head-grouping,
// p nt-stored once) -> out proj.

#define NTOK 2048
#define DMODEL 1024
#define NHEAD 16
#define DKH 64

typedef __attribute__((ext_vector_type(8))) short bf16x8;
typedef __attribute__((ext_vector_type(4))) float f32x4;

__device__ __forceinline__ unsigned short f2bf(float x) {
  unsigned int u = __builtin_bit_cast(unsigned int, x);
  u += 0x7fffu + ((u >> 16) & 1u);   // RNE
  return (unsigned short)(u >> 16);
}

__device__ __forceinline__ void gl16(const void* g, void* l) {
  __builtin_amdgcn_global_load_lds((const __attribute__((address_space(1))) void*)g,
                                   (__attribute__((address_space(3))) void*)l, 16, 0, 0);
}

// Async-stage ROWS x 64 bf16 (128B rows) into LDS, linear dest + source-side XOR.
template<int ROWS>
__device__ __forceinline__ void stage_async(const unsigned short* src, int ld,
                                            char* lds, int w, int lane) {
  constexpr int RPW = ROWS / 4;
#pragma unroll
  for (int i = 0; i < RPW / 8; ++i) {
    const int row = w * RPW + i * 8 + (lane >> 3);
    const unsigned short* g = src + (size_t)row * ld + (((lane & 7) ^ (row & 7)) * 8);
    gl16(g, lds + (size_t)(w * RPW + i * 8) * 128);
  }
}

__device__ __forceinline__ bf16x8 ldsfrag(const char* lds, int r, int kb) {
  return *(const bf16x8*)(lds + r * 128 + (kb ^ ((r & 7) << 4)));
}
__device__ __forceinline__ bf16x8 ldsfrag256(const char* lds, int r, int kb) {
  return *(const bf16x8*)(lds + r * 256 + (kb ^ ((r & 7) << 4)));
}

// ---------------- convert f32 -> bf16 (7 arrays) + mask bias (z==7) --------
struct CvtP {
  const float* src[7];
  unsigned short* dst[7];
  int n8[8];
  const int* mask;
  float* mbias;
};
__global__ __launch_bounds__(256) void cvt_all(CvtP P) {
  const int a = blockIdx.z;
  const int i = blockIdx.x * 256 + threadIdx.x;
  if (i >= P.n8[a]) return;
  if (a == 7) {
#pragma unroll
    for (int r = 0; r < 8; ++r) {
      int j = i * 8 + r;
      P.mbias[j] = P.mask[j] ? 0.0f : -1e30f;
    }
    return;
  }
  const float4* s = (const float4*)P.src[a];
  float4 v0 = s[i * 2], v1 = s[i * 2 + 1];
  ushort4 h0, h1;
  h0.x = f2bf(v0.x); h0.y = f2bf(v0.y); h0.z = f2bf(v0.z); h0.w = f2bf(v0.w);
  h1.x = f2bf(v1.x); h1.y = f2bf(v1.y); h1.z = f2bf(v1.z); h1.w = f2bf(v1.w);
  ((ushort4*)P.dst[a])[i * 2] = h0;
  ((ushort4*)P.dst[a])[i * 2 + 1] = h1;
}

// ---------------- GEMM: C[m,n] = sum_k A[m,k]B[n,k] + bias[n] ---------------
struct GemmP2 {
  const unsigned short* A[3];
  const unsigned short* B[3];
  const float* bias[3];
  unsigned short* Cb16;
  float* Cf32;
  unsigned short* VTd;
  long long sC;
  int lda, ldb, ldc, Nn, K;
};

template<int BM, bool OUTF32, bool VTRANS>
__global__ __launch_bounds__(256) void gemm_glds(GemmP2 P) {
  constexpr int BN = 128, WN = 64, FN = 4;
  constexpr int WM = BM / 2, FM = WM / 16;
  __shared__ char ldsA[BM * 128];
  __shared__ char ldsB[BN * 128];
  const int tid = threadIdx.x;
  const int lane = tid & 63, w = tid >> 6;
  const int l15 = lane & 15, lhi = lane >> 4;
  const int z = blockIdx.z;
  const int zi = (gridDim.z == 3) ? z : 0;
  const int ntn = P.Nn / BN;
  const int m0 = ((int)blockIdx.x / ntn) * BM;
  const int n0 = ((int)blockIdx.x % ntn) * BN;
  const unsigned short* Ab = P.A[zi] + (size_t)m0 * P.lda;
  const unsigned short* Bb = P.B[zi] + (size_t)n0 * P.ldb;
  const int wm = w >> 1, wn = w & 1;

  f32x4 acc[FM][FN] = {};
  for (int k0 = 0; k0 < P.K; k0 += 64) {
    stage_async<BM>(Ab + k0, P.lda, ldsA, w, lane);
    stage_async<BN>(Bb + k0, P.ldb, ldsB, w, lane);
    __syncthreads();
#pragma unroll
    for (int kk = 0; kk < 2; ++kk) {
      const int kb = kk * 64 + lhi * 16;
      bf16x8 a[FM], b[FN];
#pragma unroll
      for (int i = 0; i < FM; ++i) a[i] = ldsfrag(ldsA, wm * WM + i * 16 + l15, kb);
#pragma unroll
      for (int j = 0; j < FN; ++j) b[j] = ldsfrag(ldsB, wn * WN + j * 16 + l15, kb);
#pragma unroll
      for (int i = 0; i < FM; ++i)
#pragma unroll
        for (int j = 0; j < FN; ++j)
          acc[i][j] = __builtin_amdgcn_mfma_f32_16x16x32_bf16(a[i], b[j], acc[i][j], 0, 0, 0);
    }
    __syncthreads();
  }

  const int rbase = m0 + wm * WM + lhi * 4;
  const int cbase = n0 + wn * WN + l15;
  if (VTRANS && z == 2) {
#pragma unroll
    for (int j = 0; j < FN; ++j) {
      const int col = cbase + j * 16;
      const float badd = P.bias[zi][col];
#pragma unroll
      for (int i = 0; i < FM; ++i) {
        ushort4 t;
        t.x = f2bf(acc[i][j][0] + badd); t.y = f2bf(acc[i][j][1] + badd);
        t.z = f2bf(acc[i][j][2] + badd); t.w = f2bf(acc[i][j][3] + badd);
        *(ushort4*)(P.VTd + (size_t)col * NTOK + rbase + i * 16) = t;
      }
    }
    return;
  }
#pragma unroll
  for (int j = 0; j < FN; ++j) {
    const int col = cbase + j * 16;
    const float badd = P.bias[zi] ? P.bias[zi][col] : 0.0f;
#pragma unroll
    for (int i = 0; i < FM; ++i) {
#pragma unroll
      for (int rg = 0; rg < 4; ++rg) {
        const int row = rbase + i * 16 + rg;
        const float v = acc[i][j][rg] + badd;
        if constexpr (OUTF32)
          P.Cf32[(size_t)row * P.ldc + col] = v;
        else
          P.Cb16[(size_t)z * P.sC + (size_t)row * P.ldc + col] = f2bf(v);
      }
    }
  }
}

// ---------------- fused attention (barrier-free) ----------------------------
// Grid 512 blocks x 256 thr; block id decodes to (head-pair XCD group, q0):
//   h = 2*(id&7) + ((id>>3)&1), q0 = (id>>4)*64  -> all blocks of heads
//   {2r,2r+1} land on XCD r (id%8 heuristic), so K/V/Q slices stay L2-resident.
// Each wave owns 16 q-rows. K/V/Q MFMA fragments are loaded DIRECTLY from
// global (each K-row slice = one 128B line). Only P is in LDS (wave-private
// rows -> no __syncthreads anywhere in the loops, no vmcnt drains).
// Pass A: rsum of exp2(s*C + mbias) (swapped QK: lane-local row sums).
// Pass B: recompute S, p = exp2(arg + lr) -> nt f32x4 store (p written ONCE),
//         pack bf16 -> wave-private LDS P tile -> PV MFMA -> X bf16.
__global__ __launch_bounds__(256) void attn3(const unsigned short* __restrict__ QP,
                                             const unsigned short* __restrict__ KP,
                                             const unsigned short* __restrict__ VT,
                                             const float* __restrict__ mbias,
                                             float* __restrict__ p,
                                             unsigned short* __restrict__ XB) {
  __shared__ char ldsP[64 * 256];
  const int tid = threadIdx.x;
  const int lane = tid & 63, w = tid >> 6;
  const int l15 = lane & 15, lhi = lane >> 4;
  const int id = blockIdx.x;
  const int h = 2 * (id & 7) + ((id >> 3) & 1);
  const int q0 = (id >> 4) * 64;
  const int mrow = w * 16 + l15;          // row within the 64-row q block
  const int qrow = q0 + mrow;
  constexpr float CEXP = 0.1803368801111204f;  // log2(e)/8

  // Q fragments direct from global (B-frag: lane holds Q[qrow][kk*32+lhi*8 ..+8])
  const unsigned short* Qr = QP + (size_t)qrow * DMODEL + h * DKH;
  bf16x8 qf0 = *(const bf16x8*)(Qr + lhi * 8);
  bf16x8 qf1 = *(const bf16x8*)(Qr + 32 + lhi * 8);

  // K fragment base: A-frag row l15 (+js*16+j0), k-slice lhi*8 (+kk*32)
  const unsigned short* Kb = KP + (size_t)l15 * DMODEL + h * DKH + lhi * 8;
  const unsigned short* Vb = VT + ((size_t)h * DKH + l15) * NTOK + lhi * 8;

  // ---- pass A: row sums ----
  float rsum = 0.0f;
  for (int it = 0; it < 16; ++it) {
    const int j0 = it * 128;
    f32x4 sacc[8] = {};
#pragma unroll
    for (int js = 0; js < 8; ++js) {
      const unsigned short* kp = Kb + (size_t)(j0 + js * 16) * DMODEL;
      bf16x8 kf0 = *(const bf16x8*)(kp);
      bf16x8 kf1 = *(const bf16x8*)(kp + 32);
      sacc[js] = __builtin_amdgcn_mfma_f32_16x16x32_bf16(kf0, qf0, sacc[js], 0, 0, 0);
      sacc[js] = __builtin_amdgcn_mfma_f32_16x16x32_bf16(kf1, qf1, sacc[js], 0, 0, 0);
    }
    const float* mb = mbias + j0;
#pragma unroll
    for (int js = 0; js < 8; ++js) {
      float4 m4 = *(const float4*)(mb + js * 16 + lhi * 4);
      rsum += exp2f(sacc[js][0] * CEXP + m4.x);
      rsum += exp2f(sacc[js][1] * CEXP + m4.y);
      rsum += exp2f(sacc[js][2] * CEXP + m4.z);
      rsum += exp2f(sacc[js][3] * CEXP + m4.w);
    }
  }
  rsum += __shfl_xor(rsum, 16, 64);
  rsum += __shfl_xor(rsum, 32, 64);
  const float lr = -log2f(rsum);

  // ---- pass B: write p (nt, once) + PV ----
  float* prow = p + ((size_t)h * NTOK + qrow) * NTOK;
  f32x4 xacc[4] = {};
  for (int it = 0; it < 16; ++it) {
    const int j0 = it * 128;
    f32x4 sacc[8] = {};
#pragma unroll
    for (int js = 0; js < 8; ++js) {
      const unsigned short* kp = Kb + (size_t)(j0 + js * 16) * DMODEL;
      bf16x8 kf0 = *(const bf16x8*)(kp);
      bf16x8 kf1 = *(const bf16x8*)(kp + 32);
      sacc[js] = __builtin_amdgcn_mfma_f32_16x16x32_bf16(kf0, qf0, sacc[js], 0, 0, 0);
      sacc[js] = __builtin_amdgcn_mfma_f32_16x16x32_bf16(kf1, qf1, sacc[js], 0, 0, 0);
    }
    const float* mb = mbias + j0;
#pragma unroll
    for (int js = 0; js < 8; ++js) {
      float4 m4 = *(const float4*)(mb + js * 16 + lhi * 4);
      f32x4 e;
      e[0] = exp2f(sacc[js][0] * CEXP + (m4.x + lr));
      e[1] = exp2f(sacc[js][1] * CEXP + (m4.y + lr));
      e[2] = exp2f(sacc[js][2] * CEXP + (m4.z + lr));
      e[3] = exp2f(sacc[js][3] * CEXP + (m4.w + lr));
      __builtin_nontemporal_store(e, (f32x4*)(prow + j0 + js * 16 + lhi * 4));
      ushort4 pb;
      pb.x = f2bf(e[0]); pb.y = f2bf(e[1]); pb.z = f2bf(e[2]); pb.w = f2bf(e[3]);
      // wave-private row: no barrier between this write and the PV read
      *(ushort4*)(ldsP + mrow * 256 + ((js * 32 + lhi * 8) ^ ((mrow & 7) << 4))) = pb;
    }
#pragma unroll
    for (int jk = 0; jk < 4; ++jk) {
      bf16x8 pf = ldsfrag256(ldsP, mrow, jk * 64 + lhi * 16);
#pragma unroll
      for (int dd = 0; dd < 4; ++dd) {
        bf16x8 vf = *(const bf16x8*)(Vb + (size_t)dd * 16 * NTOK + j0 + jk * 32);
        xacc[dd] = __builtin_amdgcn_mfma_f32_16x16x32_bf16(vf, pf, xacc[dd], 0, 0, 0);
      }
    }
  }

  unsigned short* xrow = XB + (size_t)qrow * DMODEL + h * DKH;
#pragma unroll
  for (int dd = 0; dd < 4; ++dd) {
    ushort4 xb;
    xb.x = f2bf(xacc[dd][0]); xb.y = f2bf(xacc[dd][1]);
    xb.z = f2bf(xacc[dd][2]); xb.w = f2bf(xacc[dd][3]);
    *(ushort4*)(xrow + dd * 16 + lhi * 4) = xb;
  }
}

extern "C" void kernel_launch(void* const* d_in, const int* in_sizes, int n_in,
                              void* d_out, int out_size, void* d_ws, size_t ws_size,
                              hipStream_t stream) {
  (void)in_sizes; (void)n_in; (void)out_size; (void)ws_size;
  const float* query = (const float*)d_in[0];
  const float* key_  = (const float*)d_in[1];
  const float* value = (const float*)d_in[2];
  const int*   mask  = (const int*)d_in[3];
  const float* Wq = (const float*)d_in[4];
  const float* bq = (const float*)d_in[5];
  const float* Wk = (const float*)d_in[6];
  const float* bk = (const float*)d_in[7];
  const float* Wv = (const float*)d_in[8];
  const float* bv = (const float*)d_in[9];
  const float* Wo = (const float*)d_in[10];
  const float* bo = (const float*)d_in[11];

  float* out = (float*)d_out;
  float* p = out + (size_t)NTOK * DMODEL;

  char* ws = (char*)d_ws;
  unsigned short* QP  = (unsigned short*)(ws);                 // 4MB
  unsigned short* KP  = (unsigned short*)(ws + (4u << 20));    // 4MB
  unsigned short* VT  = (unsigned short*)(ws + (8u << 20));    // 4MB (16,64,2048)
  unsigned short* XB  = (unsigned short*)(ws + (12u << 20));   // 4MB
  unsigned short* qB  = (unsigned short*)(ws + (16u << 20));   // 4MB
  unsigned short* kB  = (unsigned short*)(ws + (20u << 20));
  unsigned short* vB  = (unsigned short*)(ws + (24u << 20));
  unsigned short* WqB = (unsigned short*)(ws + (28u << 20));   // 2MB each
  unsigned short* WkB = (unsigned short*)(ws + (30u << 20));
  unsigned short* WvB = (unsigned short*)(ws + (32u << 20));
  unsigned short* WoB = (unsigned short*)(ws + (34u << 20));
  float* mbias = (float*)(ws + (36u << 20));                   // 8KB

  // 1. convert everything to bf16 + mask bias
  {
    CvtP C = {};
    C.src[0] = query; C.dst[0] = qB;  C.n8[0] = NTOK * DMODEL / 8;
    C.src[1] = key_;  C.dst[1] = kB;  C.n8[1] = NTOK * DMODEL / 8;
    C.src[2] = value; C.dst[2] = vB;  C.n8[2] = NTOK * DMODEL / 8;
    C.src[3] = Wq;    C.dst[3] = WqB; C.n8[3] = DMODEL * DMODEL / 8;
    C.src[4] = Wk;    C.dst[4] = WkB; C.n8[4] = DMODEL * DMODEL / 8;
    C.src[5] = Wv;    C.dst[5] = WvB; C.n8[5] = DMODEL * DMODEL / 8;
    C.src[6] = Wo;    C.dst[6] = WoB; C.n8[6] = DMODEL * DMODEL / 8;
    C.n8[7] = NTOK / 8;
    C.mask = mask; C.mbias = mbias;
    cvt_all<<<dim3(1024, 1, 8), 256, 0, stream>>>(C);
  }
  // 2. QKV projections (z=2 -> V stored transposed into VT)
  {
    GemmP2 P = {};
    P.A[0] = qB; P.A[1] = kB; P.A[2] = vB;
    P.B[0] = WqB; P.B[1] = WkB; P.B[2] = WvB;
    P.bias[0] = bq; P.bias[1] = bk; P.bias[2] = bv;
    P.Cb16 = QP; P.VTd = VT; P.sC = (long long)NTOK * DMODEL;
    P.lda = DMODEL; P.ldb = DMODEL; P.ldc = DMODEL; P.Nn = DMODEL; P.K = DMODEL;
    gemm_glds<128, false, true>
        <<<dim3((NTOK / 128) * (DMODEL / 128), 1, 3), 256, 0, stream>>>(P);
  }
  // 3. fused attention (barrier-free, XCD head-grouped)
  attn3<<<dim3(512), 256, 0, stream>>>(QP, KP, VT, mbias, p, XB);
  // 4. out projection
  {
    GemmP2 P = {};
    P.A[0] = XB; P.B[0] = WoB; P.bias[0] = bo;
    P.Cf32 = out; P.sC = 0;
    P.lda = DMODEL; P.ldb = DMODEL; P.ldc = DMODEL; P.Nn = DMODEL; P.K = DMODEL;
    gemm_glds<64, true, false>
        <<<dim3((NTOK / 64) * (DMODEL / 128), 1, 1), 256, 0, stream>>>(P);
  }
}

// Round 7
// 156.559 us; speedup vs baseline: 2.0641x; 2.0641x over previous
//
#include <hip/hip_runtime.h>

// MHA forward: H=16, N=2048, d_model=1024, d_k=64.
// d_out = [ out (2048x1024 f32) | p_attn (16x2048x2048 f32) ]
// Pipeline: cvt(f32->bf16 + mask bias) -> QKV proj (gload_lds GEMM, V stored
// transposed) -> fused attn4 (XCD head-grouped; K/V LDS-staged dbuf via
// gload_lds; swapped QK^T; bf16 P tile doubles as transpose buffer so p is
// NT-stored f32 COALESCED, written once) -> out proj.

#define NTOK 2048
#define DMODEL 1024
#define NHEAD 16
#define DKH 64

typedef __attribute__((ext_vector_type(8))) short bf16x8;
typedef __attribute__((ext_vector_type(4))) float f32x4;
typedef __attribute__((ext_vector_type(2))) float f32x2;

__device__ __forceinline__ unsigned short f2bf(float x) {
  unsigned int u = __builtin_bit_cast(unsigned int, x);
  u += 0x7fffu + ((u >> 16) & 1u);   // RNE
  return (unsigned short)(u >> 16);
}

__device__ __forceinline__ void gl16(const void* g, void* l) {
  __builtin_amdgcn_global_load_lds((const __attribute__((address_space(1))) void*)g,
                                   (__attribute__((address_space(3))) void*)l, 16, 0, 0);
}

// Async-stage ROWS x 64 bf16 (128B rows) into LDS, linear dest + source-XOR swizzle.
template<int ROWS>
__device__ __forceinline__ void stage_async(const unsigned short* src, int ld,
                                            char* lds, int w, int lane) {
  constexpr int RPW = ROWS / 4;
#pragma unroll
  for (int i = 0; i < RPW / 8; ++i) {
    const int row = w * RPW + i * 8 + (lane >> 3);
    const unsigned short* g = src + (size_t)row * ld + (((lane & 7) ^ (row & 7)) * 8);
    gl16(g, lds + (size_t)(w * RPW + i * 8) * 128);
  }
}

// Async-stage 64 rows x 128 bf16 (256B rows), ld = NTOK (V^T tiles).
__device__ __forceinline__ void stage_v(const unsigned short* src, char* lds, int w, int lane) {
#pragma unroll
  for (int i = 0; i < 4; ++i) {
    const int row = w * 16 + i * 4 + (lane >> 4);
    const int ck = lane & 15;
    const unsigned short* g = src + (size_t)row * NTOK + ((ck ^ (row & 7)) * 8);
    gl16(g, lds + (size_t)(w * 16 + i * 4) * 256);
  }
}

__device__ __forceinline__ bf16x8 ldsfrag(const char* lds, int r, int kb) {
  return *(const bf16x8*)(lds + r * 128 + (kb ^ ((r & 7) << 4)));
}
__device__ __forceinline__ bf16x8 ldsfrag256(const char* lds, int r, int kb) {
  return *(const bf16x8*)(lds + r * 256 + (kb ^ ((r & 7) << 4)));
}

// ---------------- convert f32 -> bf16 (7 arrays) + mask bias (z==7) --------
struct CvtP {
  const float* src[7];
  unsigned short* dst[7];
  int n8[8];
  const int* mask;
  float* mbias;
};
__global__ __launch_bounds__(256) void cvt_all(CvtP P) {
  const int a = blockIdx.z;
  const int i = blockIdx.x * 256 + threadIdx.x;
  if (i >= P.n8[a]) return;
  if (a == 7) {
#pragma unroll
    for (int r = 0; r < 8; ++r) {
      int j = i * 8 + r;
      P.mbias[j] = P.mask[j] ? 0.0f : -1e30f;
    }
    return;
  }
  const float4* s = (const float4*)P.src[a];
  float4 v0 = s[i * 2], v1 = s[i * 2 + 1];
  ushort4 h0, h1;
  h0.x = f2bf(v0.x); h0.y = f2bf(v0.y); h0.z = f2bf(v0.z); h0.w = f2bf(v0.w);
  h1.x = f2bf(v1.x); h1.y = f2bf(v1.y); h1.z = f2bf(v1.z); h1.w = f2bf(v1.w);
  ((ushort4*)P.dst[a])[i * 2] = h0;
  ((ushort4*)P.dst[a])[i * 2 + 1] = h1;
}

// ---------------- GEMM: C[m,n] = sum_k A[m,k]B[n,k] + bias[n] ---------------
struct GemmP2 {
  const unsigned short* A[3];
  const unsigned short* B[3];
  const float* bias[3];
  unsigned short* Cb16;
  float* Cf32;
  unsigned short* VTd;
  long long sC;
  int lda, ldb, ldc, Nn, K;
};

template<int BM, bool OUTF32, bool VTRANS>
__global__ __launch_bounds__(256) void gemm_glds(GemmP2 P) {
  constexpr int BN = 128, WN = 64, FN = 4;
  constexpr int WM = BM / 2, FM = WM / 16;
  __shared__ char ldsA[BM * 128];
  __shared__ char ldsB[BN * 128];
  const int tid = threadIdx.x;
  const int lane = tid & 63, w = tid >> 6;
  const int l15 = lane & 15, lhi = lane >> 4;
  const int z = blockIdx.z;
  const int zi = (gridDim.z == 3) ? z : 0;
  const int ntn = P.Nn / BN;
  const int m0 = ((int)blockIdx.x / ntn) * BM;
  const int n0 = ((int)blockIdx.x % ntn) * BN;
  const unsigned short* Ab = P.A[zi] + (size_t)m0 * P.lda;
  const unsigned short* Bb = P.B[zi] + (size_t)n0 * P.ldb;
  const int wm = w >> 1, wn = w & 1;

  f32x4 acc[FM][FN] = {};
  for (int k0 = 0; k0 < P.K; k0 += 64) {
    stage_async<BM>(Ab + k0, P.lda, ldsA, w, lane);
    stage_async<BN>(Bb + k0, P.ldb, ldsB, w, lane);
    __syncthreads();
#pragma unroll
    for (int kk = 0; kk < 2; ++kk) {
      const int kb = kk * 64 + lhi * 16;
      bf16x8 a[FM], b[FN];
#pragma unroll
      for (int i = 0; i < FM; ++i) a[i] = ldsfrag(ldsA, wm * WM + i * 16 + l15, kb);
#pragma unroll
      for (int j = 0; j < FN; ++j) b[j] = ldsfrag(ldsB, wn * WN + j * 16 + l15, kb);
#pragma unroll
      for (int i = 0; i < FM; ++i)
#pragma unroll
        for (int j = 0; j < FN; ++j)
          acc[i][j] = __builtin_amdgcn_mfma_f32_16x16x32_bf16(a[i], b[j], acc[i][j], 0, 0, 0);
    }
    __syncthreads();
  }

  const int rbase = m0 + wm * WM + lhi * 4;
  const int cbase = n0 + wn * WN + l15;
  if (VTRANS && z == 2) {
#pragma unroll
    for (int j = 0; j < FN; ++j) {
      const int col = cbase + j * 16;
      const float badd = P.bias[zi][col];
#pragma unroll
      for (int i = 0; i < FM; ++i) {
        ushort4 t;
        t.x = f2bf(acc[i][j][0] + badd); t.y = f2bf(acc[i][j][1] + badd);
        t.z = f2bf(acc[i][j][2] + badd); t.w = f2bf(acc[i][j][3] + badd);
        *(ushort4*)(P.VTd + (size_t)col * NTOK + rbase + i * 16) = t;
      }
    }
    return;
  }
#pragma unroll
  for (int j = 0; j < FN; ++j) {
    const int col = cbase + j * 16;
    const float badd = P.bias[zi] ? P.bias[zi][col] : 0.0f;
#pragma unroll
    for (int i = 0; i < FM; ++i) {
#pragma unroll
      for (int rg = 0; rg < 4; ++rg) {
        const int row = rbase + i * 16 + rg;
        const float v = acc[i][j][rg] + badd;
        if constexpr (OUTF32)
          P.Cf32[(size_t)row * P.ldc + col] = v;
        else
          P.Cb16[(size_t)z * P.sC + (size_t)row * P.ldc + col] = f2bf(v);
      }
    }
  }
}

// ---------------- fused attention v4 ---------------------------------------
// Grid 512: h = 2*(id&7)+((id>>3)&1), q0 = (id>>4)*64  (XCD head-pair groups,
// proven FETCH 50->6 MB). 4 waves x 16 q-rows. K (128j x 64dk) and V^T
// (64d x 128j) LDS-staged dbuf via gload_lds (wave-shared, coalesced).
// Swapped QK^T -> lane-local row sums. P tile (bf16, wave-private rows) feeds
// PV MFMA AND acts as transpose buffer: p is NT-stored f32 from LDS rows,
// 512B contiguous per instruction, written exactly once.
__global__ __launch_bounds__(256) void attn4(const unsigned short* __restrict__ QP,
                                             const unsigned short* __restrict__ KP,
                                             const unsigned short* __restrict__ VT,
                                             const float* __restrict__ mbias,
                                             float* __restrict__ p,
                                             unsigned short* __restrict__ XB) {
  __shared__ char ldsK[2][128 * 128];
  __shared__ char ldsV[2][64 * 256];
  __shared__ char ldsP[64 * 256];
  const int tid = threadIdx.x;
  const int lane = tid & 63, w = tid >> 6;
  const int l15 = lane & 15, lhi = lane >> 4;
  const int id = blockIdx.x;
  const int h = 2 * (id & 7) + ((id >> 3) & 1);
  const int q0 = (id >> 4) * 64;
  const int mrow = w * 16 + l15;
  constexpr float CEXP = 0.1803368801111204f;  // log2(e)/8

  // Q -> registers (staged through ldsP; wave stages its own rows)
  stage_async<64>(QP + (size_t)q0 * DMODEL + h * DKH, DMODEL, (char*)ldsP, w, lane);
  __syncthreads();
  bf16x8 qf0 = ldsfrag((char*)ldsP, mrow, lhi * 16);
  bf16x8 qf1 = ldsfrag((char*)ldsP, mrow, 64 + lhi * 16);

  const unsigned short* Kh = KP + h * DKH;
  const unsigned short* Vh = VT + (size_t)h * DKH * NTOK;

  // ---- pass A: row sums ----
  float rsum = 0.0f;
  __syncthreads();
  stage_async<128>(Kh, DMODEL, ldsK[0], w, lane);
  __syncthreads();
  int b = 0;
  for (int it = 0; it < 16; ++it) {
    if (it < 15)
      stage_async<128>(Kh + (size_t)(it + 1) * 128 * DMODEL, DMODEL, ldsK[b ^ 1], w, lane);
    f32x4 sacc[8] = {};
#pragma unroll
    for (int kk = 0; kk < 2; ++kk)
#pragma unroll
      for (int js = 0; js < 8; ++js) {
        bf16x8 kf = ldsfrag(ldsK[b], js * 16 + l15, kk * 64 + lhi * 16);
        sacc[js] = __builtin_amdgcn_mfma_f32_16x16x32_bf16(kf, kk ? qf1 : qf0, sacc[js], 0, 0, 0);
      }
    const float* mb = mbias + it * 128;
#pragma unroll
    for (int js = 0; js < 8; ++js) {
      float4 m4 = *(const float4*)(mb + js * 16 + lhi * 4);
      rsum += exp2f(sacc[js][0] * CEXP + m4.x);
      rsum += exp2f(sacc[js][1] * CEXP + m4.y);
      rsum += exp2f(sacc[js][2] * CEXP + m4.z);
      rsum += exp2f(sacc[js][3] * CEXP + m4.w);
    }
    __syncthreads();
    b ^= 1;
  }
  rsum += __shfl_xor(rsum, 16, 64);
  rsum += __shfl_xor(rsum, 32, 64);
  const float lr = -log2f(rsum);

  // ---- pass B: QK^T again, p via LDS transpose (coalesced NT f32), PV ----
  f32x4 xacc[4] = {};
  stage_async<128>(Kh, DMODEL, ldsK[0], w, lane);
  stage_v(Vh, ldsV[0], w, lane);
  __syncthreads();
  b = 0;
  for (int it = 0; it < 16; ++it) {
    const int j0 = it * 128;
    if (it < 15) {
      stage_async<128>(Kh + (size_t)(j0 + 128) * DMODEL, DMODEL, ldsK[b ^ 1], w, lane);
      stage_v(Vh + j0 + 128, ldsV[b ^ 1], w, lane);
    }
    f32x4 sacc[8] = {};
#pragma unroll
    for (int kk = 0; kk < 2; ++kk)
#pragma unroll
      for (int js = 0; js < 8; ++js) {
        bf16x8 kf = ldsfrag(ldsK[b], js * 16 + l15, kk * 64 + lhi * 16);
        sacc[js] = __builtin_amdgcn_mfma_f32_16x16x32_bf16(kf, kk ? qf1 : qf0, sacc[js], 0, 0, 0);
      }
    const float* mb = mbias + j0;
#pragma unroll
    for (int js = 0; js < 8; ++js) {
      float4 m4 = *(const float4*)(mb + js * 16 + lhi * 4);
      ushort4 pb;
      pb.x = f2bf(exp2f(sacc[js][0] * CEXP + (m4.x + lr)));
      pb.y = f2bf(exp2f(sacc[js][1] * CEXP + (m4.y + lr)));
      pb.z = f2bf(exp2f(sacc[js][2] * CEXP + (m4.z + lr)));
      pb.w = f2bf(exp2f(sacc[js][3] * CEXP + (m4.w + lr)));
      // wave-private row: no barrier between this write and same-wave reads
      *(ushort4*)(ldsP + mrow * 256 + ((js * 32 + lhi * 8) ^ ((mrow & 7) << 4))) = pb;
    }
    // PV from bf16 P tile
#pragma unroll
    for (int jk = 0; jk < 4; ++jk) {
      bf16x8 pf = ldsfrag256(ldsP, mrow, jk * 64 + lhi * 16);
#pragma unroll
      for (int dd = 0; dd < 4; ++dd) {
        bf16x8 vf = ldsfrag256(ldsV[b], dd * 16 + l15, jk * 64 + lhi * 16);
        xacc[dd] = __builtin_amdgcn_mfma_f32_16x16x32_bf16(vf, pf, xacc[dd], 0, 0, 0);
      }
    }
    // p-store: read own wave's P rows back row-major -> 512B contiguous NT
#pragma unroll
    for (int r = 0; r < 16; ++r) {
      const int row = w * 16 + r;
      const unsigned int u =
          *(const unsigned int*)(ldsP + row * 256 + ((lane * 4) ^ ((row & 7) << 4)));
      f32x2 f;
      f[0] = __builtin_bit_cast(float, u << 16);
      f[1] = __builtin_bit_cast(float, u & 0xffff0000u);
      __builtin_nontemporal_store(
          f, (f32x2*)(p + ((size_t)h * NTOK + q0 + row) * NTOK + j0 + lane * 2));
    }
    __syncthreads();
    b ^= 1;
  }

  unsigned short* xrow = XB + (size_t)(q0 + mrow) * DMODEL + h * DKH;
#pragma unroll
  for (int dd = 0; dd < 4; ++dd) {
    ushort4 xb;
    xb.x = f2bf(xacc[dd][0]); xb.y = f2bf(xacc[dd][1]);
    xb.z = f2bf(xacc[dd][2]); xb.w = f2bf(xacc[dd][3]);
    *(ushort4*)(xrow + dd * 16 + lhi * 4) = xb;
  }
}

extern "C" void kernel_launch(void* const* d_in, const int* in_sizes, int n_in,
                              void* d_out, int out_size, void* d_ws, size_t ws_size,
                              hipStream_t stream) {
  (void)in_sizes; (void)n_in; (void)out_size; (void)ws_size;
  const float* query = (const float*)d_in[0];
  const float* key_  = (const float*)d_in[1];
  const float* value = (const float*)d_in[2];
  const int*   mask  = (const int*)d_in[3];
  const float* Wq = (const float*)d_in[4];
  const float* bq = (const float*)d_in[5];
  const float* Wk = (const float*)d_in[6];
  const float* bk = (const float*)d_in[7];
  const float* Wv = (const float*)d_in[8];
  const float* bv = (const float*)d_in[9];
  const float* Wo = (const float*)d_in[10];
  const float* bo = (const float*)d_in[11];

  float* out = (float*)d_out;
  float* p = out + (size_t)NTOK * DMODEL;

  char* ws = (char*)d_ws;
  unsigned short* QP  = (unsigned short*)(ws);                 // 4MB
  unsigned short* KP  = (unsigned short*)(ws + (4u << 20));    // 4MB
  unsigned short* VT  = (unsigned short*)(ws + (8u << 20));    // 4MB (16,64,2048)
  unsigned short* XB  = (unsigned short*)(ws + (12u << 20));   // 4MB
  unsigned short* qB  = (unsigned short*)(ws + (16u << 20));   // 4MB
  unsigned short* kB  = (unsigned short*)(ws + (20u << 20));
  unsigned short* vB  = (unsigned short*)(ws + (24u << 20));
  unsigned short* WqB = (unsigned short*)(ws + (28u << 20));   // 2MB each
  unsigned short* WkB = (unsigned short*)(ws + (30u << 20));
  unsigned short* WvB = (unsigned short*)(ws + (32u << 20));
  unsigned short* WoB = (unsigned short*)(ws + (34u << 20));
  float* mbias = (float*)(ws + (36u << 20));                   // 8KB

  // 1. convert everything to bf16 + mask bias
  {
    CvtP C = {};
    C.src[0] = query; C.dst[0] = qB;  C.n8[0] = NTOK * DMODEL / 8;
    C.src[1] = key_;  C.dst[1] = kB;  C.n8[1] = NTOK * DMODEL / 8;
    C.src[2] = value; C.dst[2] = vB;  C.n8[2] = NTOK * DMODEL / 8;
    C.src[3] = Wq;    C.dst[3] = WqB; C.n8[3] = DMODEL * DMODEL / 8;
    C.src[4] = Wk;    C.dst[4] = WkB; C.n8[4] = DMODEL * DMODEL / 8;
    C.src[5] = Wv;    C.dst[5] = WvB; C.n8[5] = DMODEL * DMODEL / 8;
    C.src[6] = Wo;    C.dst[6] = WoB; C.n8[6] = DMODEL * DMODEL / 8;
    C.n8[7] = NTOK / 8;
    C.mask = mask; C.mbias = mbias;
    cvt_all<<<dim3(1024, 1, 8), 256, 0, stream>>>(C);
  }
  // 2. QKV projections (z=2 -> V stored transposed into VT)
  {
    GemmP2 P = {};
    P.A[0] = qB; P.A[1] = kB; P.A[2] = vB;
    P.B[0] = WqB; P.B[1] = WkB; P.B[2] = WvB;
    P.bias[0] = bq; P.bias[1] = bk; P.bias[2] = bv;
    P.Cb16 = QP; P.VTd = VT; P.sC = (long long)NTOK * DMODEL;
    P.lda = DMODEL; P.ldb = DMODEL; P.ldc = DMODEL; P.Nn = DMODEL; P.K = DMODEL;
    gemm_glds<128, false, true>
        <<<dim3((NTOK / 128) * (DMODEL / 128), 1, 3), 256, 0, stream>>>(P);
  }
  // 3. fused attention v4
  attn4<<<dim3(512), 256, 0, stream>>>(QP, KP, VT, mbias, p, XB);
  // 4. out projection
  {
    GemmP2 P = {};
    P.A[0] = XB; P.B[0] = WoB; P.bias[0] = bo;
    P.Cf32 = out; P.sC = 0;
    P.lda = DMODEL; P.ldb = DMODEL; P.ldc = DMODEL; P.Nn = DMODEL; P.K = DMODEL;
    gemm_glds<64, true, false>
        <<<dim3((NTOK / 64) * (DMODEL / 128), 1, 1), 256, 0, stream>>>(P);
  }
}

// Round 8
// 147.096 us; speedup vs baseline: 2.1968x; 1.0643x over previous
//
#include <hip/hip_runtime.h>

// MHA forward: H=16, N=2048, d_model=1024, d_k=64.
// d_out = [ out (2048x1024 f32) | p_attn (16x2048x2048 f32) ]
// Pipeline: cvt(f32->bf16 + mask bias) -> QKV proj (gload_lds GEMM, V stored
// transposed) -> fused attn5 (XCD head-grouped; K/V LDS dbuf via gload_lds;
// RAW s_barrier + COUNTED vmcnt so p NT-stores are never drained in-loop;
// bf16 P tile doubles as transpose buffer -> p written once, coalesced)
// -> out proj.

#define NTOK 2048
#define DMODEL 1024
#define NHEAD 16
#define DKH 64

typedef __attribute__((ext_vector_type(8))) short bf16x8;
typedef __attribute__((ext_vector_type(4))) float f32x4;

// counted waitcnt: waits until <= N vmem ops outstanding. "memory" clobber
// pins all memory ops across it; sched_barrier stops MFMA/alu hoisting.
#define WAITVMC(n)                                          \
  do {                                                      \
    asm volatile("s_waitcnt vmcnt(" n ")" ::: "memory");    \
    __builtin_amdgcn_sched_barrier(0);                      \
  } while (0)
#define BARRIER()                                           \
  do {                                                      \
    __builtin_amdgcn_s_barrier();                           \
    __builtin_amdgcn_sched_barrier(0);                      \
  } while (0)

__device__ __forceinline__ unsigned short f2bf(float x) {
  unsigned int u = __builtin_bit_cast(unsigned int, x);
  u += 0x7fffu + ((u >> 16) & 1u);   // RNE
  return (unsigned short)(u >> 16);
}

__device__ __forceinline__ void gl16(const void* g, void* l) {
  __builtin_amdgcn_global_load_lds((const __attribute__((address_space(1))) void*)g,
                                   (__attribute__((address_space(3))) void*)l, 16, 0, 0);
}

// Async-stage ROWS x 64 bf16 (128B rows) into LDS, linear dest + source-XOR swizzle.
template<int ROWS>
__device__ __forceinline__ void stage_async(const unsigned short* src, int ld,
                                            char* lds, int w, int lane) {
  constexpr int RPW = ROWS / 4;
#pragma unroll
  for (int i = 0; i < RPW / 8; ++i) {
    const int row = w * RPW + i * 8 + (lane >> 3);
    const unsigned short* g = src + (size_t)row * ld + (((lane & 7) ^ (row & 7)) * 8);
    gl16(g, lds + (size_t)(w * RPW + i * 8) * 128);
  }
}

// Async-stage 64 rows x 128 bf16 (256B rows), ld = NTOK (V^T tiles).
__device__ __forceinline__ void stage_v(const unsigned short* src, char* lds, int w, int lane) {
#pragma unroll
  for (int i = 0; i < 4; ++i) {
    const int row = w * 16 + i * 4 + (lane >> 4);
    const int ck = lane & 15;
    const unsigned short* g = src + (size_t)row * NTOK + ((ck ^ (row & 7)) * 8);
    gl16(g, lds + (size_t)(w * 16 + i * 4) * 256);
  }
}

__device__ __forceinline__ bf16x8 ldsfrag(const char* lds, int r, int kb) {
  return *(const bf16x8*)(lds + r * 128 + (kb ^ ((r & 7) << 4)));
}
__device__ __forceinline__ bf16x8 ldsfrag256(const char* lds, int r, int kb) {
  return *(const bf16x8*)(lds + r * 256 + (kb ^ ((r & 7) << 4)));
}

// ---------------- convert f32 -> bf16 (7 arrays) + mask bias (z==7) --------
struct CvtP {
  const float* src[7];
  unsigned short* dst[7];
  int n8[8];
  const int* mask;
  float* mbias;
};
__global__ __launch_bounds__(256) void cvt_all(CvtP P) {
  const int a = blockIdx.z;
  const int i = blockIdx.x * 256 + threadIdx.x;
  if (i >= P.n8[a]) return;
  if (a == 7) {
#pragma unroll
    for (int r = 0; r < 8; ++r) {
      int j = i * 8 + r;
      P.mbias[j] = P.mask[j] ? 0.0f : -1e30f;
    }
    return;
  }
  const float4* s = (const float4*)P.src[a];
  float4 v0 = s[i * 2], v1 = s[i * 2 + 1];
  ushort4 h0, h1;
  h0.x = f2bf(v0.x); h0.y = f2bf(v0.y); h0.z = f2bf(v0.z); h0.w = f2bf(v0.w);
  h1.x = f2bf(v1.x); h1.y = f2bf(v1.y); h1.z = f2bf(v1.z); h1.w = f2bf(v1.w);
  ((ushort4*)P.dst[a])[i * 2] = h0;
  ((ushort4*)P.dst[a])[i * 2 + 1] = h1;
}

// ---------------- GEMM: C[m,n] = sum_k A[m,k]B[n,k] + bias[n] ---------------
struct GemmP2 {
  const unsigned short* A[3];
  const unsigned short* B[3];
  const float* bias[3];
  unsigned short* Cb16;
  float* Cf32;
  unsigned short* VTd;
  long long sC;
  int lda, ldb, ldc, Nn, K;
};

template<int BM, bool OUTF32, bool VTRANS>
__global__ __launch_bounds__(256) void gemm_glds(GemmP2 P) {
  constexpr int BN = 128, WN = 64, FN = 4;
  constexpr int WM = BM / 2, FM = WM / 16;
  __shared__ char ldsA[BM * 128];
  __shared__ char ldsB[BN * 128];
  const int tid = threadIdx.x;
  const int lane = tid & 63, w = tid >> 6;
  const int l15 = lane & 15, lhi = lane >> 4;
  const int z = blockIdx.z;
  const int zi = (gridDim.z == 3) ? z : 0;
  const int ntn = P.Nn / BN;
  const int m0 = ((int)blockIdx.x / ntn) * BM;
  const int n0 = ((int)blockIdx.x % ntn) * BN;
  const unsigned short* Ab = P.A[zi] + (size_t)m0 * P.lda;
  const unsigned short* Bb = P.B[zi] + (size_t)n0 * P.ldb;
  const int wm = w >> 1, wn = w & 1;

  f32x4 acc[FM][FN] = {};
  for (int k0 = 0; k0 < P.K; k0 += 64) {
    stage_async<BM>(Ab + k0, P.lda, ldsA, w, lane);
    stage_async<BN>(Bb + k0, P.ldb, ldsB, w, lane);
    __syncthreads();
#pragma unroll
    for (int kk = 0; kk < 2; ++kk) {
      const int kb = kk * 64 + lhi * 16;
      bf16x8 a[FM], b[FN];
#pragma unroll
      for (int i = 0; i < FM; ++i) a[i] = ldsfrag(ldsA, wm * WM + i * 16 + l15, kb);
#pragma unroll
      for (int j = 0; j < FN; ++j) b[j] = ldsfrag(ldsB, wn * WN + j * 16 + l15, kb);
#pragma unroll
      for (int i = 0; i < FM; ++i)
#pragma unroll
        for (int j = 0; j < FN; ++j)
          acc[i][j] = __builtin_amdgcn_mfma_f32_16x16x32_bf16(a[i], b[j], acc[i][j], 0, 0, 0);
    }
    __syncthreads();
  }

  const int rbase = m0 + wm * WM + lhi * 4;
  const int cbase = n0 + wn * WN + l15;
  if (VTRANS && z == 2) {
#pragma unroll
    for (int j = 0; j < FN; ++j) {
      const int col = cbase + j * 16;
      const float badd = P.bias[zi][col];
#pragma unroll
      for (int i = 0; i < FM; ++i) {
        ushort4 t;
        t.x = f2bf(acc[i][j][0] + badd); t.y = f2bf(acc[i][j][1] + badd);
        t.z = f2bf(acc[i][j][2] + badd); t.w = f2bf(acc[i][j][3] + badd);
        *(ushort4*)(P.VTd + (size_t)col * NTOK + rbase + i * 16) = t;
      }
    }
    return;
  }
#pragma unroll
  for (int j = 0; j < FN; ++j) {
    const int col = cbase + j * 16;
    const float badd = P.bias[zi] ? P.bias[zi][col] : 0.0f;
#pragma unroll
    for (int i = 0; i < FM; ++i) {
#pragma unroll
      for (int rg = 0; rg < 4; ++rg) {
        const int row = rbase + i * 16 + rg;
        const float v = acc[i][j][rg] + badd;
        if constexpr (OUTF32)
          P.Cf32[(size_t)row * P.ldc + col] = v;
        else
          P.Cb16[(size_t)z * P.sC + (size_t)row * P.ldc + col] = f2bf(v);
      }
    }
  }
}

// ---------------- fused attention v5 (counted-vmcnt, raw barriers) ----------
// Grid 512: h = 2*(id&7)+((id>>3)&1), q0 = (id>>4)*64 (XCD head-pair groups).
// 4 waves x 16 q-rows; K (128j x 64dk) + V^T (64d x 128j) LDS dbuf (gload_lds).
// Sync per iter: each wave WAITVMC(N) certifies its OWN prefetch landed
// (N = #stores in flight, so p-stores are NEVER drained), then raw s_barrier.
// Prefetch issue is pinned before stores by sched_barrier so vmcnt ordering
// (oldest = prefetch) is guaranteed.
__global__ __launch_bounds__(256) void attn5(const unsigned short* __restrict__ QP,
                                             const unsigned short* __restrict__ KP,
                                             const unsigned short* __restrict__ VT,
                                             const float* __restrict__ mbias,
                                             float* __restrict__ p,
                                             unsigned short* __restrict__ XB) {
  __shared__ char ldsK[2][128 * 128];
  __shared__ char ldsV[2][64 * 256];
  __shared__ char ldsP[64 * 256];
  const int tid = threadIdx.x;
  const int lane = tid & 63, w = tid >> 6;
  const int l15 = lane & 15, lhi = lane >> 4;
  const int id = blockIdx.x;
  const int h = 2 * (id & 7) + ((id >> 3) & 1);
  const int q0 = (id >> 4) * 64;
  const int mrow = w * 16 + l15;
  constexpr float CEXP = 0.1803368801111204f;  // log2(e)/8

  // Q -> registers (staged through ldsP)
  stage_async<64>(QP + (size_t)q0 * DMODEL + h * DKH, DMODEL, ldsP, w, lane);
  __syncthreads();
  bf16x8 qf0 = ldsfrag(ldsP, mrow, lhi * 16);
  bf16x8 qf1 = ldsfrag(ldsP, mrow, 64 + lhi * 16);

  const unsigned short* Kh = KP + h * DKH;
  const unsigned short* Vh = VT + (size_t)h * DKH * NTOK;

  // ---- pass A: row sums (no stores -> exact vmcnt(0), covered by compute) --
  float rsum = 0.0f;
  stage_async<128>(Kh, DMODEL, ldsK[0], w, lane);
  int b = 0;
  for (int it = 0; it < 16; ++it) {
    WAITVMC("0");
    BARRIER();
    if (it < 15)
      stage_async<128>(Kh + (size_t)(it + 1) * 128 * DMODEL, DMODEL, ldsK[b ^ 1], w, lane);
    __builtin_amdgcn_sched_barrier(0);
    f32x4 sacc[8] = {};
#pragma unroll
    for (int kk = 0; kk < 2; ++kk)
#pragma unroll
      for (int js = 0; js < 8; ++js) {
        bf16x8 kf = ldsfrag(ldsK[b], js * 16 + l15, kk * 64 + lhi * 16);
        sacc[js] = __builtin_amdgcn_mfma_f32_16x16x32_bf16(kf, kk ? qf1 : qf0, sacc[js], 0, 0, 0);
      }
    const float* mb = mbias + it * 128;
#pragma unroll
    for (int js = 0; js < 8; ++js) {
      float4 m4 = *(const float4*)(mb + js * 16 + lhi * 4);
      rsum += exp2f(sacc[js][0] * CEXP + m4.x);
      rsum += exp2f(sacc[js][1] * CEXP + m4.y);
      rsum += exp2f(sacc[js][2] * CEXP + m4.z);
      rsum += exp2f(sacc[js][3] * CEXP + m4.w);
    }
    b ^= 1;
  }
  rsum += __shfl_xor(rsum, 16, 64);
  rsum += __shfl_xor(rsum, 32, 64);
  const float lr = -log2f(rsum);

  // ---- pass B: QK^T again; p via LDS transpose, 8 NT f32x4 stores/iter ----
  // iter i waits vmcnt(8): completes prefetch(i) [8 oldest], leaves the 8
  // stores from iter i-1 in flight. Stores retire in background.
  f32x4 xacc[4] = {};
  stage_async<128>(Kh, DMODEL, ldsK[0], w, lane);
  stage_v(Vh, ldsV[0], w, lane);
  b = 0;
  for (int it = 0; it < 16; ++it) {
    const int j0 = it * 128;
    if (it == 0) { WAITVMC("0"); } else { WAITVMC("8"); }
    BARRIER();
    if (it < 15) {
      stage_async<128>(Kh + (size_t)(j0 + 128) * DMODEL, DMODEL, ldsK[b ^ 1], w, lane);
      stage_v(Vh + j0 + 128, ldsV[b ^ 1], w, lane);
    }
    __builtin_amdgcn_sched_barrier(0);   // pin prefetch issue BEFORE stores
    f32x4 sacc[8] = {};
#pragma unroll
    for (int kk = 0; kk < 2; ++kk)
#pragma unroll
      for (int js = 0; js < 8; ++js) {
        bf16x8 kf = ldsfrag(ldsK[b], js * 16 + l15, kk * 64 + lhi * 16);
        sacc[js] = __builtin_amdgcn_mfma_f32_16x16x32_bf16(kf, kk ? qf1 : qf0, sacc[js], 0, 0, 0);
      }
    const float* mb = mbias + j0;
#pragma unroll
    for (int js = 0; js < 8; ++js) {
      float4 m4 = *(const float4*)(mb + js * 16 + lhi * 4);
      ushort4 pb;
      pb.x = f2bf(exp2f(sacc[js][0] * CEXP + (m4.x + lr)));
      pb.y = f2bf(exp2f(sacc[js][1] * CEXP + (m4.y + lr)));
      pb.z = f2bf(exp2f(sacc[js][2] * CEXP + (m4.z + lr)));
      pb.w = f2bf(exp2f(sacc[js][3] * CEXP + (m4.w + lr)));
      // wave-private row: no barrier between this write and same-wave reads
      *(ushort4*)(ldsP + mrow * 256 + ((js * 32 + lhi * 8) ^ ((mrow & 7) << 4))) = pb;
    }
    // p-store: 8 insts, each = 2 rows x 32 lanes x 16B (512B/row contiguous)
#pragma unroll
    for (int r = 0; r < 8; ++r) {
      const int row = w * 16 + r * 2 + (lane >> 5);
      const uint2 u =
          *(const uint2*)(ldsP + row * 256 + (((lane & 31) * 8) ^ ((row & 7) << 4)));
      f32x4 f;
      f[0] = __builtin_bit_cast(float, u.x << 16);
      f[1] = __builtin_bit_cast(float, u.x & 0xffff0000u);
      f[2] = __builtin_bit_cast(float, u.y << 16);
      f[3] = __builtin_bit_cast(float, u.y & 0xffff0000u);
      __builtin_nontemporal_store(
          f, (f32x4*)(p + ((size_t)h * NTOK + q0 + row) * NTOK + j0 + (lane & 31) * 4));
    }
    // PV from bf16 P tile
#pragma unroll
    for (int jk = 0; jk < 4; ++jk) {
      bf16x8 pf = ldsfrag256(ldsP, mrow, jk * 64 + lhi * 16);
#pragma unroll
      for (int dd = 0; dd < 4; ++dd) {
        bf16x8 vf = ldsfrag256(ldsV[b], dd * 16 + l15, jk * 64 + lhi * 16);
        xacc[dd] = __builtin_amdgcn_mfma_f32_16x16x32_bf16(vf, pf, xacc[dd], 0, 0, 0);
      }
    }
    b ^= 1;
  }

  unsigned short* xrow = XB + (size_t)(q0 + mrow) * DMODEL + h * DKH;
#pragma unroll
  for (int dd = 0; dd < 4; ++dd) {
    ushort4 xb;
    xb.x = f2bf(xacc[dd][0]); xb.y = f2bf(xacc[dd][1]);
    xb.z = f2bf(xacc[dd][2]); xb.w = f2bf(xacc[dd][3]);
    *(ushort4*)(xrow + dd * 16 + lhi * 4) = xb;
  }
}

extern "C" void kernel_launch(void* const* d_in, const int* in_sizes, int n_in,
                              void* d_out, int out_size, void* d_ws, size_t ws_size,
                              hipStream_t stream) {
  (void)in_sizes; (void)n_in; (void)out_size; (void)ws_size;
  const float* query = (const float*)d_in[0];
  const float* key_  = (const float*)d_in[1];
  const float* value = (const float*)d_in[2];
  const int*   mask  = (const int*)d_in[3];
  const float* Wq = (const float*)d_in[4];
  const float* bq = (const float*)d_in[5];
  const float* Wk = (const float*)d_in[6];
  const float* bk = (const float*)d_in[7];
  const float* Wv = (const float*)d_in[8];
  const float* bv = (const float*)d_in[9];
  const float* Wo = (const float*)d_in[10];
  const float* bo = (const float*)d_in[11];

  float* out = (float*)d_out;
  float* p = out + (size_t)NTOK * DMODEL;

  char* ws = (char*)d_ws;
  unsigned short* QP  = (unsigned short*)(ws);                 // 4MB
  unsigned short* KP  = (unsigned short*)(ws + (4u << 20));    // 4MB
  unsigned short* VT  = (unsigned short*)(ws + (8u << 20));    // 4MB (16,64,2048)
  unsigned short* XB  = (unsigned short*)(ws + (12u << 20));   // 4MB
  unsigned short* qB  = (unsigned short*)(ws + (16u << 20));   // 4MB
  unsigned short* kB  = (unsigned short*)(ws + (20u << 20));
  unsigned short* vB  = (unsigned short*)(ws + (24u << 20));
  unsigned short* WqB = (unsigned short*)(ws + (28u << 20));   // 2MB each
  unsigned short* WkB = (unsigned short*)(ws + (30u << 20));
  unsigned short* WvB = (unsigned short*)(ws + (32u << 20));
  unsigned short* WoB = (unsigned short*)(ws + (34u << 20));
  float* mbias = (float*)(ws + (36u << 20));                   // 8KB

  // 1. convert everything to bf16 + mask bias
  {
    CvtP C = {};
    C.src[0] = query; C.dst[0] = qB;  C.n8[0] = NTOK * DMODEL / 8;
    C.src[1] = key_;  C.dst[1] = kB;  C.n8[1] = NTOK * DMODEL / 8;
    C.src[2] = value; C.dst[2] = vB;  C.n8[2] = NTOK * DMODEL / 8;
    C.src[3] = Wq;    C.dst[3] = WqB; C.n8[3] = DMODEL * DMODEL / 8;
    C.src[4] = Wk;    C.dst[4] = WkB; C.n8[4] = DMODEL * DMODEL / 8;
    C.src[5] = Wv;    C.dst[5] = WvB; C.n8[5] = DMODEL * DMODEL / 8;
    C.src[6] = Wo;    C.dst[6] = WoB; C.n8[6] = DMODEL * DMODEL / 8;
    C.n8[7] = NTOK / 8;
    C.mask = mask; C.mbias = mbias;
    cvt_all<<<dim3(1024, 1, 8), 256, 0, stream>>>(C);
  }
  // 2. QKV projections (z=2 -> V stored transposed into VT)
  {
    GemmP2 P = {};
    P.A[0] = qB; P.A[1] = kB; P.A[2] = vB;
    P.B[0] = WqB; P.B[1] = WkB; P.B[2] = WvB;
    P.bias[0] = bq; P.bias[1] = bk; P.bias[2] = bv;
    P.Cb16 = QP; P.VTd = VT; P.sC = (long long)NTOK * DMODEL;
    P.lda = DMODEL; P.ldb = DMODEL; P.ldc = DMODEL; P.Nn = DMODEL; P.K = DMODEL;
    gemm_glds<128, false, true>
        <<<dim3((NTOK / 128) * (DMODEL / 128), 1, 3), 256, 0, stream>>>(P);
  }
  // 3. fused attention v5
  attn5<<<dim3(512), 256, 0, stream>>>(QP, KP, VT, mbias, p, XB);
  // 4. out projection
  {
    GemmP2 P = {};
    P.A[0] = XB; P.B[0] = WoB; P.bias[0] = bo;
    P.Cf32 = out; P.sC = 0;
    P.lda = DMODEL; P.ldb = DMODEL; P.ldc = DMODEL; P.Nn = DMODEL; P.K = DMODEL;
    gemm_glds<64, true, false>
        <<<dim3((NTOK / 64) * (DMODEL / 128), 1, 1), 256, 0, stream>>>(P);
  }
}